// Round 8
// baseline (376.453 us; speedup 1.0000x reference)
//
#include <hip/hip_runtime.h>
#include <cstdint>
#include <cstddef>

#define B_ 2
#define T_ 2048
#define D_ 2048
#define HQ_ 16
#define HKV_ 8
#define HD_ 128

typedef __attribute__((ext_vector_type(8))) short short8;
typedef __attribute__((ext_vector_type(8))) unsigned short ushort8;
typedef __attribute__((ext_vector_type(4))) float f32x4;
typedef __attribute__((ext_vector_type(2))) unsigned short ushort2v;
typedef __attribute__((ext_vector_type(4))) unsigned short ushort4v;
typedef __attribute__((ext_vector_type(2))) float float2v;
typedef __attribute__((ext_vector_type(4))) float float4v;

__device__ __forceinline__ unsigned short f2bf(float f) {
  unsigned int u = __builtin_bit_cast(unsigned int, f);
  u += 0x7fffu + ((u >> 16) & 1u);
  return (unsigned short)(u >> 16);
}
__device__ __forceinline__ float bf2f(unsigned short h) {
  unsigned int u = ((unsigned int)h) << 16;
  return __builtin_bit_cast(float, u);
}

#if defined(__has_builtin)
#if __has_builtin(__builtin_amdgcn_global_load_lds)
#define HAS_GLL 1
#endif
#endif
#ifndef HAS_GLL
#define HAS_GLL 0
#endif

// async global->LDS, 16B per lane; LDS dest = base (wave-uniform) + lane*16
__device__ __forceinline__ void gll16(const void* g, void* l) {
#if HAS_GLL
  __builtin_amdgcn_global_load_lds((const __attribute__((address_space(1))) void*)g,
                                   (__attribute__((address_space(3))) void*)l, 16, 0, 0);
#else
  *(ushort8*)((char*)l + (threadIdx.x & 63) * 16) = *(const ushort8*)g;
#endif
}

// ---------------- fused cast f32 -> bf16, v2: 16 elems/thread, block-uniform tensor ----------------
__global__ __launch_bounds__(256) void cast_all(const float* __restrict__ x,
                                                const float* __restrict__ wq,
                                                const float* __restrict__ wk,
                                                const float* __restrict__ wv,
                                                const float* __restrict__ wo,
                                                unsigned short* __restrict__ xb,
                                                unsigned short* __restrict__ wqkv,
                                                unsigned short* __restrict__ wob) {
  const int base = blockIdx.x * 4096;
  const float* s;
  unsigned short* d;
  int soff, doff;
  if (base < 8388608)       { s = x;  soff = base;            d = xb;   doff = base; }
  else if (base < 12582912) { s = wq; soff = base - 8388608;  d = wqkv; doff = base - 8388608; }
  else if (base < 14680064) { s = wk; soff = base - 12582912; d = wqkv; doff = base - 8388608; }
  else if (base < 16777216) { s = wv; soff = base - 14680064; d = wqkv; doff = base - 8388608; }
  else                      { s = wo; soff = base - 16777216; d = wob;  doff = base - 16777216; }
#pragma unroll
  for (int k = 0; k < 4; k++) {
    const int off = (k * 256 + threadIdx.x) * 4;
    float4v v = *(const float4v*)(s + soff + off);
    ushort4v o; o.x = f2bf(v.x); o.y = f2bf(v.y); o.z = f2bf(v.z); o.w = f2bf(v.w);
    *(ushort4v*)(d + doff + off) = o;
  }
}

// ================= GEMM v4: BMx256, BK=64, 8 waves, 8-phase + register ds_read PREFETCH ===========
// v3 (round 5, verified) + one change: each phase's A/B fragment ds_reads are issued INSIDE the
// previous phase's MFMA region (after its lgkmcnt(0)+sched_barrier), into double-buffered register
// sets, so ~120cyc LDS latency hides under MFMA instead of serializing (v3 measured MfmaUtil 37%,
// model: 8 x 120cyc serial latency/iter vs 1240cyc MFMA -> 37%. matches).
// Hazard ledger (per-phase prefetch -> restage of same region):
//   ph1 pre B1(b0f): restaged ph3-gap (read done by ph2 barrier)     OK
//   ph2 pre A1(b0f): restaged ph4-gap (done by ph3 barrier)          OK
//   ph4 pre A0,B0(b1f): issued AFTER VMW that landed prev k3; restaged ph5-gap (done ph5 barrier) OK
//   ph5 pre B1(b1f): restaged ph7-gap (done ph6 barrier)             OK
//   ph6 pre A1(b1f): restaged ph8-gap (done ph7 barrier)             OK
//   ph8 pre A0,B0(b0f,k2): issued AFTER VMW that landed k2; restaged next-ph2-gap OK
// Stage placement / VMW counts / prologue / peel identical to v3 (proof in round 3).
#define PH_SYNC { __builtin_amdgcn_s_barrier(); \
                  asm volatile("s_waitcnt lgkmcnt(0)" ::: "memory"); \
                  __builtin_amdgcn_sched_barrier(0); \
                  __builtin_amdgcn_s_setprio(1); }
#define PH_END  { __builtin_amdgcn_s_setprio(0); \
                  __builtin_amdgcn_s_barrier(); \
                  __builtin_amdgcn_sched_barrier(0); }
#define SBAR __builtin_amdgcn_sched_barrier(0)

#define PREF_A(AA, BUF, QM) { \
  _Pragma("unroll") for (int ii = 0; ii < BM/64; ii++) { \
    _Pragma("unroll") for (int ks = 0; ks < 2; ks++) \
      AA[ii][ks] = *(const short8*)&Abuf[BUF][((QM)*(BM/2) + wm*(BM/4) + ii*16 + c)*64 + (((ks*4+g)^cs)*8)]; } }

#define PREF_B(BB, BUF, QN) { \
  _Pragma("unroll") for (int jj = 0; jj < 2; jj++) { \
    _Pragma("unroll") for (int ks = 0; ks < 2; ks++) \
      BB[jj][ks] = *(const short8*)&Bbuf[BUF][((QN)*128 + wn*32 + jj*16 + c)*64 + (((ks*4+g)^cs)*8)]; } }

#define MM(QM, QN, AA, BB) { \
  _Pragma("unroll") for (int ii = 0; ii < BM/64; ii++) { \
    _Pragma("unroll") for (int jj = 0; jj < 2; jj++) { \
      f32x4 t_ = __builtin_amdgcn_mfma_f32_16x16x32_bf16(AA[ii][0], BB[jj][0], acc[(QM)*(BM/64)+ii][(QN)*2+jj], 0, 0, 0); \
      acc[(QM)*(BM/64)+ii][(QN)*2+jj] = __builtin_amdgcn_mfma_f32_16x16x32_bf16(AA[ii][1], BB[jj][1], t_, 0, 0, 0); } } }

template<int BM, int M, int N, int K, bool BF16_OUT>
__global__ __launch_bounds__(512, 2) void gemm8(const unsigned short* __restrict__ A,
                                                const unsigned short* __restrict__ W,
                                                void* __restrict__ Cout) {
  __shared__ __align__(16) unsigned short Abuf[2][BM * 64];
  __shared__ __align__(16) unsigned short Bbuf[2][256 * 64];
  const int tid = threadIdx.x;
  const int lane = tid & 63;
  const int wv = tid >> 6;        // 0..7
  const int g = lane >> 4;        // 0..3
  const int c = lane & 15;
  const int cs = c & 7;
  const int wm = wv >> 2;         // 0..1
  const int wn = wv & 3;          // 0..3

  constexpr int SH_Q = (BM == 256) ? 7 : 6;   // log2(BM/2)
  constexpr int SH_W = SH_Q - 1;              // log2(BM/4)

  constexpr int NT = N / 256;
  constexpr int NWG = (M / BM) * NT;
  constexpr int CHUNK = NWG / 8;  // NWG % 8 == 0 for both instantiations
  const int bid = blockIdx.x;
  const int swz = (bid & 7) * CHUNK + (bid >> 3);
  const int m0 = (swz / NT) * BM;
  const int n0 = (swz % NT) * 256;

  const int prl = wv * 8 + (lane >> 3);   // physical row offset within call
  const int scl = lane & 7;               // stored chunk slot
#define STA(BUF, P0, KO) { \
    int pr_ = (P0) + prl; \
    int lr_ = ((pr_ >> SH_W) & 1) * (BM/2) + ((pr_ >> SH_Q) & 1) * (BM/4) + (pr_ & (BM/4 - 1)); \
    int lc_ = (scl ^ (pr_ & 7)) * 8; \
    gll16(&A[(size_t)(m0 + lr_) * K + (KO) + lc_], &Abuf[BUF][(P0) * 64 + wv * 512]); }
#define STB(BUF, P0, KO) { \
    int pr_ = (P0) + prl; \
    int lr_ = ((pr_ >> 5) & 3) * 64 + ((pr_ >> 7) & 1) * 32 + (pr_ & 31); \
    int lc_ = (scl ^ (pr_ & 7)) * 8; \
    gll16(&W[(size_t)(n0 + lr_) * K + (KO) + lc_], &Bbuf[BUF][(P0) * 64 + wv * 512]); }

#define STAGE_PH2(BUF, KO) { if constexpr (BM == 256) { STA(BUF, 0, KO); STA(BUF, 64, KO); } \
                             else { STA(BUF, 0, KO); } \
                             STB(BUF, 0, KO); STB(BUF, 64, KO); }
#define STAGE_PH3(BUF, KO) { STB(BUF, 128, KO); STB(BUF, 192, KO); }
#define STAGE_PH4(BUF, KO) { if constexpr (BM == 256) { STA(BUF, 128, KO); STA(BUF, 192, KO); } \
                             else { STA(BUF, 64, KO); } }
#define VMW { if constexpr (BM == 256) { asm volatile("s_waitcnt vmcnt(8)" ::: "memory"); } \
              else { asm volatile("s_waitcnt vmcnt(6)" ::: "memory"); } }

  short8 a0[BM/64][2], a1[BM/64][2], b0[2][2], b1[2][2];
  f32x4 acc[BM/32][4];
#pragma unroll
  for (int i = 0; i < BM/32; i++)
#pragma unroll
    for (int j = 0; j < 4; j++) acc[i][j] = (f32x4)0.0f;

  // prologue: fully stage K-tiles 0 (buf0) and 1 (buf1); prefetch ph1's regs
  STAGE_PH2(0, 0); STAGE_PH3(0, 0); STAGE_PH4(0, 0);
  STAGE_PH2(1, 64); STAGE_PH3(1, 64); STAGE_PH4(1, 64);
  VMW;                               // K-tile 0 landed
  __builtin_amdgcn_s_barrier();
  PREF_A(a0, 0, 0); PREF_B(b0, 0, 0);

  constexpr int NITER = K / 128;   // 16
  for (int it = 0; it < NITER - 1; ++it) {
    const int k2 = it * 128 + 128;   // K-tile 2it+2 -> buf0
    const int k3 = k2 + 64;          // K-tile 2it+3 -> buf1
    // ph1: use a0,b0 ; prefetch b1 <- B1(buf0)
    PH_SYNC; PREF_B(b1, 0, 1); SBAR; MM(0, 0, a0, b0); PH_END;
    STAGE_PH2(0, k2);
    // ph2: use a0,b1 ; prefetch a1 <- A1(buf0)
    PH_SYNC; PREF_A(a1, 0, 1); SBAR; MM(0, 1, a0, b1); PH_END;
    STAGE_PH3(0, k2);
    // ph3: use a1,b1
    PH_SYNC; MM(1, 1, a1, b1); PH_END;
    STAGE_PH4(0, k2);
    VMW;
    // ph4: use a1,b0 ; prefetch a0 <- A0(buf1), b1 <- B0(buf1)  [prev k3 landed at VMW]
    PH_SYNC; PREF_A(a0, 1, 0); PREF_B(b1, 1, 0); SBAR; MM(1, 0, a1, b0); PH_END;
    // ph5: use a0,b1 ; prefetch b0 <- B1(buf1)
    PH_SYNC; PREF_B(b0, 1, 1); SBAR; MM(0, 0, a0, b1); PH_END;
    STAGE_PH2(1, k3);
    // ph6: use a0,b0 ; prefetch a1 <- A1(buf1)
    PH_SYNC; PREF_A(a1, 1, 1); SBAR; MM(0, 1, a0, b0); PH_END;
    STAGE_PH3(1, k3);
    // ph7: use a1,b0
    PH_SYNC; MM(1, 1, a1, b0); PH_END;
    STAGE_PH4(1, k3);
    VMW;
    // ph8: use a1,b1 ; prefetch a0 <- A0(buf0,k2), b0 <- B0(buf0,k2)  [k2 landed at VMW]
    PH_SYNC; PREF_A(a0, 0, 0); PREF_B(b0, 0, 0); SBAR; MM(1, 0, a1, b1); PH_END;
  }
  // ---- peeled final iteration (K-tiles 30,31; no stages) ----
  PH_SYNC; PREF_B(b1, 0, 1); SBAR; MM(0, 0, a0, b0); PH_END;
  PH_SYNC; PREF_A(a1, 0, 1); SBAR; MM(0, 1, a0, b1); PH_END;
  PH_SYNC; MM(1, 1, a1, b1); PH_END;
  asm volatile("s_waitcnt vmcnt(0)" ::: "memory");   // K-tile 31 (buf1) landed
  PH_SYNC; PREF_A(a0, 1, 0); PREF_B(b1, 1, 0); SBAR; MM(1, 0, a1, b0); PH_END;
  PH_SYNC; PREF_B(b0, 1, 1); SBAR; MM(0, 0, a0, b1); PH_END;
  PH_SYNC; PREF_A(a1, 1, 1); SBAR; MM(0, 1, a0, b0); PH_END;
  PH_SYNC; MM(1, 1, a1, b0); PH_END;
  PH_SYNC; MM(1, 0, a1, b1); PH_END;

  // epilogue: C/D layout col=lane&15, row=g*4+r (verified)
#pragma unroll
  for (int I = 0; I < BM/32; I++)
#pragma unroll
    for (int J = 0; J < 4; J++)
#pragma unroll
      for (int r = 0; r < 4; r++) {
        int row = m0 + wm * (BM/2) + I * 16 + g * 4 + r;
        int col = n0 + wn * 64 + J * 16 + c;
        if (BF16_OUT)
          ((unsigned short*)Cout)[(size_t)row * N + col] = f2bf(acc[I][J][r]);
        else
          ((float*)Cout)[(size_t)row * N + col] = acc[I][J][r];
      }
#undef STA
#undef STB
#undef STAGE_PH2
#undef STAGE_PH3
#undef STAGE_PH4
#undef VMW
}

// ---------------- fused RMSNorm+RoPE (blocks 0..4095) and V-transpose (blocks 4096..4607) ----------------
__global__ __launch_bounds__(256) void rope_and_vt(const unsigned short* __restrict__ qkv,
                                                   const float* __restrict__ cosT,
                                                   const float* __restrict__ sinT,
                                                   const float* __restrict__ q_scale,
                                                   const float* __restrict__ k_scale,
                                                   unsigned short* __restrict__ Qb,
                                                   unsigned short* __restrict__ Kb,
                                                   unsigned short* __restrict__ Vt) {
  __shared__ unsigned short lds[128 * 65];
  const int tid = threadIdx.x;
  if (blockIdx.x < 4096) {
    // ---- RMSNorm + RoPE path ----
    const int lane = tid & 63;
    const int wvq = tid >> 6;
    const int row = blockIdx.x;   // b*T + t
    const int b = row >> 11;
    const int t = row & 2047;
    const int d0 = lane * 2;

    const float2v cs = *(const float2v*)&cosT[t * 128 + d0];
    const float2v sn = *(const float2v*)&sinT[t * 128 + d0];
    const float2v qsc = *(const float2v*)&q_scale[d0];
    const float2v ksc = *(const float2v*)&k_scale[d0];
    const float sgn = (lane < 32) ? -1.0f : 1.0f;
    const unsigned short* base = qkv + (size_t)row * 4096;

#pragma unroll
    for (int s6 = 0; s6 < 6; s6++) {
      const int slot = wvq * 6 + s6;
      const bool isQ = slot < 16;
      const unsigned short* src = base + (isQ ? slot * 128 : 2048 + (slot - 16) * 128);
      ushort2v u = *(const ushort2v*)&src[d0];
      float x0 = bf2f(u.x), x1 = bf2f(u.y);
      float ss = x0 * x0 + x1 * x1;
      ss += __shfl_xor(ss, 1);  ss += __shfl_xor(ss, 2);  ss += __shfl_xor(ss, 4);
      ss += __shfl_xor(ss, 8);  ss += __shfl_xor(ss, 16); ss += __shfl_xor(ss, 32);
      float rinv = rsqrtf(ss * (1.0f / 128.0f) + 1e-6f);
      float2v scv = isQ ? qsc : ksc;
      float xn0 = x0 * rinv * scv.x;
      float xn1 = x1 * rinv * scv.y;
      float o0 = __shfl_xor(xn0, 32);
      float o1 = __shfl_xor(xn1, 32);
      float r0v = xn0 * cs.x + sgn * o0 * sn.x;
      float r1v = xn1 * cs.y + sgn * o1 * sn.y;
      ushort2v out; out.x = f2bf(r0v); out.y = f2bf(r1v);
      unsigned short* dst;
      if (isQ) dst = Qb + ((size_t)(b * HQ_ + slot) * T_ + t) * HD_;
      else     dst = Kb + ((size_t)(b * HKV_ + (slot - 16)) * T_ + t) * HD_;
      *(ushort2v*)&dst[d0] = out;
    }
  } else {
    // ---- V transpose path: (b,t,kv,d) -> Vt[b,kv,d,t] ----
    const int blk = blockIdx.x - 4096;     // 0..511
    const int tblk = blk & 31;
    const int kv = (blk >> 5) & 7;
    const int b = blk >> 8;
    const int t0 = tblk * 64;
    const int r = tid >> 2;
    const int seg = tid & 3;
    const unsigned short* src = qkv + (size_t)(b * T_ + t0 + r) * 4096 + 3072 + kv * 128;
    for (int i = 0; i < 4; i++) {
      int cc = seg * 32 + i * 8;
      ushort8 v = *(const ushort8*)&src[cc];
      for (int q = 0; q < 8; q++) lds[(cc + q) * 65 + r] = v[q];
    }
    __syncthreads();
    const int cI = tid >> 1;
    const int rs = (tid & 1) * 32;
    unsigned short* dst = Vt + ((size_t)(b * HKV_ + kv) * HD_ + cI) * T_ + t0 + rs;
    const unsigned short* srow = &lds[cI * 65 + rs];
    for (int j = 0; j < 32; j += 4) {
      ushort4v v; v.x = srow[j]; v.y = srow[j + 1]; v.z = srow[j + 2]; v.w = srow[j + 3];
      *(ushort4v*)&dst[j] = v;
    }
  }
}

// ---------------- Flash attention v5: double-buffered K/V, uniform work (verified) ----------------
__global__ __launch_bounds__(256) void attn(const unsigned short* __restrict__ Qb,
                                            const unsigned short* __restrict__ Kb,
                                            const unsigned short* __restrict__ Vt,
                                            unsigned short* __restrict__ ctxb) {
  __shared__ __align__(16) unsigned short Ks[2][64 * 128];  // [key][hd], chunk-swizzled
  __shared__ __align__(16) unsigned short Vs[2][128 * 64];  // [hd][key], chunk-swizzled
  __shared__ __align__(16) unsigned short Ps[4][16 * 72];   // per-wave P, stride 72 (pad)
  const int tid = threadIdx.x;
  const int lane = tid & 63;
  const int wv = tid >> 6;
  const int g = lane >> 4;
  const int c = lane & 15;

  const int blk = blockIdx.x;            // 0..511
  const int kv = blk & 7;
  const int idx = blk >> 3;              // 0..63
  const int p = idx >> 2;                // 0..15 pair index
  const int b = (idx >> 1) & 1;
  const int h = kv * 2 + (idx & 1);

  const unsigned short* Kh = Kb + (size_t)(b * HKV_ + kv) * T_ * HD_;
  const unsigned short* Vh = Vt + (size_t)(b * HKV_ + kv) * HD_ * T_;
  const float scale = 0.08838834764831845f;  // 1/sqrt(128)

#define STAGE_KV(BF, KT) { \
  _Pragma("unroll") for (int i_ = 0; i_ < 4; i_++) { \
    const int ch_ = wv * 256 + i_ * 64 + lane; \
    const int rK_ = ch_ >> 4, cK_ = ch_ & 15; \
    gll16(Kh + (size_t)((KT) * 64 + rK_) * HD_ + (cK_ ^ (rK_ & 7)) * 8, \
          Ks[BF] + (size_t)(wv * 256 + i_ * 64) * 8); \
    const int rV_ = ch_ >> 3, cV_ = ch_ & 7; \
    gll16(Vh + (size_t)rV_ * T_ + (KT) * 64 + (cV_ ^ (rV_ & 7)) * 8, \
          Vs[BF] + (size_t)(wv * 256 + i_ * 64) * 8); } }

  for (int ph = 0; ph < 2; ph++) {
    const int qb = ph ? (31 - p) : p;    // 64-row q-block index
    const int nkt = qb + 1;
    const unsigned short* Qh = Qb + ((size_t)(b * HQ_ + h) * T_ + qb * 64 + wv * 16) * HD_;

    short8 aq[4];
#pragma unroll
    for (int dk = 0; dk < 4; dk++) aq[dk] = *(const short8*)&Qh[c * HD_ + dk * 32 + g * 8];

    f32x4 acc[8];
#pragma unroll
    for (int dc = 0; dc < 8; dc++) acc[dc] = (f32x4)0.0f;
    float lp[4] = {0.0f, 0.0f, 0.0f, 0.0f};

    // prologue: stage kt=0 into buf0 (prev ph's last barrier protects buf reuse)
    STAGE_KV(0, 0);
    __syncthreads();

    for (int kt = 0; kt < nkt; kt++) {
      const int cur = kt & 1;
      if (kt + 1 < nkt) { STAGE_KV(cur ^ 1, kt + 1); }   // block-uniform condition
      __builtin_amdgcn_sched_barrier(0);                 // pin stage-issue before compute

      f32x4 s[4];
#pragma unroll
      for (int kf = 0; kf < 4; kf++) s[kf] = (f32x4)0.0f;
      __builtin_amdgcn_s_setprio(1);
#pragma unroll
      for (int dk = 0; dk < 4; dk++) {
#pragma unroll
        for (int kf = 0; kf < 4; kf++) {
          short8 bk = *(const short8*)&Ks[cur][(kf * 16 + c) * 128 + ((dk * 4 + g) ^ (c & 7)) * 8];
          s[kf] = __builtin_amdgcn_mfma_f32_16x16x32_bf16(aq[dk], bk, s[kf], 0, 0, 0);
        }
      }
      __builtin_amdgcn_s_setprio(0);

      const bool diag = (kt == nkt - 1);
#pragma unroll
      for (int kf = 0; kf < 4; kf++) {
#pragma unroll
        for (int r = 0; r < 4; r++) {
          float pv = __expf(s[kf][r] * scale);
          if (diag) {
            int key = kt * 64 + kf * 16 + c;
            int rowq = qb * 64 + wv * 16 + g * 4 + r;
            if (key > rowq) pv = 0.0f;
          }
          lp[r] += pv;
          Ps[wv][(g * 4 + r) * 72 + kf * 16 + c] = f2bf(pv);
        }
      }

      short8 ap[2];
      ap[0] = *(const short8*)&Ps[wv][c * 72 + g * 8];
      ap[1] = *(const short8*)&Ps[wv][c * 72 + 32 + g * 8];
      __builtin_amdgcn_s_setprio(1);
#pragma unroll
      for (int dc = 0; dc < 8; dc++) {
#pragma unroll
        for (int kf2 = 0; kf2 < 2; kf2++) {
          short8 bv = *(const short8*)&Vs[cur][(dc * 16 + c) * 64 + ((kf2 * 4 + g) ^ (c & 7)) * 8];
          acc[dc] = __builtin_amdgcn_mfma_f32_16x16x32_bf16(ap[kf2], bv, acc[dc], 0, 0, 0);
        }
      }
      __builtin_amdgcn_s_setprio(0);

      __syncthreads();   // drains vmcnt(0): kt+1's tile landed; buf cur free for kt+2
    }

#pragma unroll
    for (int r = 0; r < 4; r++) {
      float l = lp[r];
      l += __shfl_xor(l, 1); l += __shfl_xor(l, 2);
      l += __shfl_xor(l, 4); l += __shfl_xor(l, 8);
      float inv = 1.0f / l;
      int row = b * T_ + qb * 64 + wv * 16 + g * 4 + r;
#pragma unroll
      for (int dc = 0; dc < 8; dc++)
        ctxb[(size_t)row * (HQ_ * HD_) + h * HD_ + dc * 16 + c] = f2bf(acc[dc][r] * inv);
    }
  }
#undef STAGE_KV
}

extern "C" void kernel_launch(void* const* d_in, const int* in_sizes, int n_in,
                              void* d_out, int out_size, void* d_ws, size_t ws_size,
                              hipStream_t stream) {
  const float* x = (const float*)d_in[0];
  const float* cosT = (const float*)d_in[2];
  const float* sinT = (const float*)d_in[3];
  const float* Wq = (const float*)d_in[4];
  const float* Wk = (const float*)d_in[5];
  const float* Wv = (const float*)d_in[6];
  const float* Wo = (const float*)d_in[7];
  const float* q_scale = (const float*)d_in[8];
  const float* k_scale = (const float*)d_in[9];

  char* ws = (char*)d_ws;
  unsigned short* qkv  = (unsigned short*)(ws + 0);
  unsigned short* ctxb = qkv;                                  // alias: qkv dead before attn
  unsigned short* xb   = (unsigned short*)(ws + 33554432);
  unsigned short* wqkv = (unsigned short*)(ws + 50331648);
  unsigned short* wob  = (unsigned short*)(ws + 67108864);
  unsigned short* Qb   = (unsigned short*)(ws + 75497472);
  unsigned short* Kb   = (unsigned short*)(ws + 92274688);
  unsigned short* Vt   = (unsigned short*)(ws + 100663296);

  cast_all<<<5120, 256, 0, stream>>>(x, Wq, Wk, Wv, Wo, xb, wqkv, wob);
  gemm8<256, 4096, 4096, 2048, true><<<256, 512, 0, stream>>>(xb, wqkv, qkv);
  rope_and_vt<<<4608, 256, 0, stream>>>(qkv, cosT, sinT, q_scale, k_scale, Qb, Kb, Vt);
  attn<<<512, 256, 0, stream>>>(Qb, Kb, Vt, ctxb);
  gemm8<128, 4096, 2048, 2048, false><<<256, 512, 0, stream>>>(ctxb, wob, d_out);
}

// Round 10
// 332.563 us; speedup vs baseline: 1.1320x; 1.1320x over previous
//
#include <hip/hip_runtime.h>
#include <cstdint>
#include <cstddef>

#define B_ 2
#define T_ 2048
#define D_ 2048
#define HQ_ 16
#define HKV_ 8
#define HD_ 128

typedef __attribute__((ext_vector_type(8))) short short8;
typedef __attribute__((ext_vector_type(8))) unsigned short ushort8;
typedef __attribute__((ext_vector_type(4))) float f32x4;
typedef __attribute__((ext_vector_type(2))) unsigned short ushort2v;
typedef __attribute__((ext_vector_type(4))) unsigned short ushort4v;
typedef __attribute__((ext_vector_type(2))) float float2v;
typedef __attribute__((ext_vector_type(4))) float float4v;

__device__ __forceinline__ unsigned short f2bf(float f) {
  unsigned int u = __builtin_bit_cast(unsigned int, f);
  u += 0x7fffu + ((u >> 16) & 1u);
  return (unsigned short)(u >> 16);
}
__device__ __forceinline__ float bf2f(unsigned short h) {
  unsigned int u = ((unsigned int)h) << 16;
  return __builtin_bit_cast(float, u);
}

#if defined(__has_builtin)
#if __has_builtin(__builtin_amdgcn_global_load_lds)
#define HAS_GLL 1
#endif
#endif
#ifndef HAS_GLL
#define HAS_GLL 0
#endif

// async global->LDS, 16B per lane; LDS dest = base (wave-uniform) + lane*16
__device__ __forceinline__ void gll16(const void* g, void* l) {
#if HAS_GLL
  __builtin_amdgcn_global_load_lds((const __attribute__((address_space(1))) void*)g,
                                   (__attribute__((address_space(3))) void*)l, 16, 0, 0);
#else
  *(ushort8*)((char*)l + (threadIdx.x & 63) * 16) = *(const ushort8*)g;
#endif
}

// ---------------- fused cast f32 -> bf16, v2: 16 elems/thread, block-uniform tensor ----------------
__global__ __launch_bounds__(256) void cast_all(const float* __restrict__ x,
                                                const float* __restrict__ wq,
                                                const float* __restrict__ wk,
                                                const float* __restrict__ wv,
                                                const float* __restrict__ wo,
                                                unsigned short* __restrict__ xb,
                                                unsigned short* __restrict__ wqkv,
                                                unsigned short* __restrict__ wob) {
  const int base = blockIdx.x * 4096;
  const float* s;
  unsigned short* d;
  int soff, doff;
  if (base < 8388608)       { s = x;  soff = base;            d = xb;   doff = base; }
  else if (base < 12582912) { s = wq; soff = base - 8388608;  d = wqkv; doff = base - 8388608; }
  else if (base < 14680064) { s = wk; soff = base - 12582912; d = wqkv; doff = base - 8388608; }
  else if (base < 16777216) { s = wv; soff = base - 14680064; d = wqkv; doff = base - 8388608; }
  else                      { s = wo; soff = base - 16777216; d = wob;  doff = base - 16777216; }
#pragma unroll
  for (int k = 0; k < 4; k++) {
    const int off = (k * 256 + threadIdx.x) * 4;
    float4v v = *(const float4v*)(s + soff + off);
    ushort4v o; o.x = f2bf(v.x); o.y = f2bf(v.y); o.z = f2bf(v.z); o.w = f2bf(v.w);
    *(ushort4v*)(d + doff + off) = o;
  }
}

// ================= GEMM v3: BMx256 tile, BK=64, 8 waves, 8-phase pipelined =================
// REVERTED to round-5/7 verified version. Round-8 lesson (banked): register ds_read
// prefetch is infeasible at BM=256 — acc(128 AGPR)+arch(128 VGPR) is the full 256-budget;
// +96 prefetch regs spilled to scratch (WRITE_SIZE 32.8->93.3 MB, 73.5->121 us).
#define PH_SYNC { __builtin_amdgcn_s_barrier(); \
                  asm volatile("s_waitcnt lgkmcnt(0)" ::: "memory"); \
                  __builtin_amdgcn_sched_barrier(0); \
                  __builtin_amdgcn_s_setprio(1); }
#define PH_END  { __builtin_amdgcn_s_setprio(0); \
                  __builtin_amdgcn_s_barrier(); \
                  __builtin_amdgcn_sched_barrier(0); }
#define SBAR __builtin_amdgcn_sched_barrier(0)

#define LDA(BUF, QM) { \
  _Pragma("unroll") for (int ii = 0; ii < BM/64; ii++) { \
    _Pragma("unroll") for (int ks = 0; ks < 2; ks++) \
      a[ii][ks] = *(const short8*)&Abuf[BUF][((QM)*(BM/2) + wm*(BM/4) + ii*16 + c)*64 + (((ks*4+g)^cs)*8)]; } }

#define LDB(BUF, QN, BB) { \
  _Pragma("unroll") for (int jj = 0; jj < 2; jj++) { \
    _Pragma("unroll") for (int ks = 0; ks < 2; ks++) \
      BB[jj][ks] = *(const short8*)&Bbuf[BUF][((QN)*128 + wn*32 + jj*16 + c)*64 + (((ks*4+g)^cs)*8)]; } }

#define MM(QM, QN, BB) { \
  _Pragma("unroll") for (int ii = 0; ii < BM/64; ii++) { \
    _Pragma("unroll") for (int jj = 0; jj < 2; jj++) { \
      f32x4 t_ = __builtin_amdgcn_mfma_f32_16x16x32_bf16(a[ii][0], BB[jj][0], acc[(QM)*(BM/64)+ii][(QN)*2+jj], 0, 0, 0); \
      acc[(QM)*(BM/64)+ii][(QN)*2+jj] = __builtin_amdgcn_mfma_f32_16x16x32_bf16(a[ii][1], BB[jj][1], t_, 0, 0, 0); } } }

template<int BM, int M, int N, int K, bool BF16_OUT>
__global__ __launch_bounds__(512, 2) void gemm8(const unsigned short* __restrict__ A,
                                                const unsigned short* __restrict__ W,
                                                void* __restrict__ Cout) {
  __shared__ __align__(16) unsigned short Abuf[2][BM * 64];
  __shared__ __align__(16) unsigned short Bbuf[2][256 * 64];
  const int tid = threadIdx.x;
  const int lane = tid & 63;
  const int wv = tid >> 6;        // 0..7
  const int g = lane >> 4;        // 0..3
  const int c = lane & 15;
  const int cs = c & 7;
  const int wm = wv >> 2;         // 0..1
  const int wn = wv & 3;          // 0..3

  constexpr int SH_Q = (BM == 256) ? 7 : 6;   // log2(BM/2)
  constexpr int SH_W = SH_Q - 1;              // log2(BM/4)

  constexpr int NT = N / 256;
  constexpr int NWG = (M / BM) * NT;
  constexpr int CHUNK = NWG / 8;
  const int bid = blockIdx.x;
  const int swz = (bid & 7) * CHUNK + (bid >> 3);
  const int m0 = (swz / NT) * BM;
  const int n0 = (swz % NT) * 256;

  const int prl = wv * 8 + (lane >> 3);   // physical row offset within call
  const int scl = lane & 7;               // stored chunk slot
#define STA(BUF, P0, KO) { \
    int pr_ = (P0) + prl; \
    int lr_ = ((pr_ >> SH_W) & 1) * (BM/2) + ((pr_ >> SH_Q) & 1) * (BM/4) + (pr_ & (BM/4 - 1)); \
    int lc_ = (scl ^ (pr_ & 7)) * 8; \
    gll16(&A[(size_t)(m0 + lr_) * K + (KO) + lc_], &Abuf[BUF][(P0) * 64 + wv * 512]); }
#define STB(BUF, P0, KO) { \
    int pr_ = (P0) + prl; \
    int lr_ = ((pr_ >> 5) & 3) * 64 + ((pr_ >> 7) & 1) * 32 + (pr_ & 31); \
    int lc_ = (scl ^ (pr_ & 7)) * 8; \
    gll16(&W[(size_t)(n0 + lr_) * K + (KO) + lc_], &Bbuf[BUF][(P0) * 64 + wv * 512]); }

#define STAGE_PH2(BUF, KO) { if constexpr (BM == 256) { STA(BUF, 0, KO); STA(BUF, 64, KO); } \
                             else { STA(BUF, 0, KO); } \
                             STB(BUF, 0, KO); STB(BUF, 64, KO); }
#define STAGE_PH3(BUF, KO) { STB(BUF, 128, KO); STB(BUF, 192, KO); }
#define STAGE_PH4(BUF, KO) { if constexpr (BM == 256) { STA(BUF, 128, KO); STA(BUF, 192, KO); } \
                             else { STA(BUF, 64, KO); } }
#define VMW { if constexpr (BM == 256) { asm volatile("s_waitcnt vmcnt(8)" ::: "memory"); } \
              else { asm volatile("s_waitcnt vmcnt(6)" ::: "memory"); } }

  short8 a[BM/64][2], b0[2][2], b1[2][2];
  f32x4 acc[BM/32][4];
#pragma unroll
  for (int i = 0; i < BM/32; i++)
#pragma unroll
    for (int j = 0; j < 4; j++) acc[i][j] = (f32x4)0.0f;

  // prologue: fully stage K-tiles 0 (buf0) and 1 (buf1)
  STAGE_PH2(0, 0); STAGE_PH3(0, 0); STAGE_PH4(0, 0);
  STAGE_PH2(1, 64); STAGE_PH3(1, 64); STAGE_PH4(1, 64);
  VMW;                               // K-tile 0 landed
  __builtin_amdgcn_s_barrier();

  constexpr int NITER = K / 128;   // 16
  for (int it = 0; it < NITER - 1; ++it) {
    const int k2 = it * 128 + 128;   // K-tile 2it+2 -> buf0
    const int k3 = k2 + 64;          // K-tile 2it+3 -> buf1
    LDA(0, 0); LDB(0, 0, b0);
    PH_SYNC; MM(0, 0, b0); PH_END;
    LDB(0, 1, b1);
    STAGE_PH2(0, k2);
    PH_SYNC; MM(0, 1, b1); PH_END;
    LDA(0, 1);
    STAGE_PH3(0, k2);
    PH_SYNC; MM(1, 1, b1); PH_END;
    STAGE_PH4(0, k2);
    VMW;
    PH_SYNC; MM(1, 0, b0); PH_END;
    LDA(1, 0); LDB(1, 0, b0);
    PH_SYNC; MM(0, 0, b0); PH_END;
    LDB(1, 1, b1);
    STAGE_PH2(1, k3);
    PH_SYNC; MM(0, 1, b1); PH_END;
    LDA(1, 1);
    STAGE_PH3(1, k3);
    PH_SYNC; MM(1, 1, b1); PH_END;
    STAGE_PH4(1, k3);
    VMW;
    PH_SYNC; MM(1, 0, b0); PH_END;
  }
  // peeled final iteration (no stages; ph4 drains)
  LDA(0, 0); LDB(0, 0, b0); PH_SYNC; MM(0, 0, b0); PH_END;
  LDB(0, 1, b1);            PH_SYNC; MM(0, 1, b1); PH_END;
  LDA(0, 1);                PH_SYNC; MM(1, 1, b1); PH_END;
  asm volatile("s_waitcnt vmcnt(0)" ::: "memory");
  PH_SYNC; MM(1, 0, b0); PH_END;
  LDA(1, 0); LDB(1, 0, b0); PH_SYNC; MM(0, 0, b0); PH_END;
  LDB(1, 1, b1);            PH_SYNC; MM(0, 1, b1); PH_END;
  LDA(1, 1);                PH_SYNC; MM(1, 1, b1); PH_END;
  PH_SYNC; MM(1, 0, b0); PH_END;

  // epilogue: C/D layout col=lane&15, row=g*4+r (verified)
#pragma unroll
  for (int I = 0; I < BM/32; I++)
#pragma unroll
    for (int J = 0; J < 4; J++)
#pragma unroll
      for (int r = 0; r < 4; r++) {
        int row = m0 + wm * (BM/2) + I * 16 + g * 4 + r;
        int col = n0 + wn * 64 + J * 16 + c;
        if (BF16_OUT)
          ((unsigned short*)Cout)[(size_t)row * N + col] = f2bf(acc[I][J][r]);
        else
          ((float*)Cout)[(size_t)row * N + col] = acc[I][J][r];
      }
#undef STA
#undef STB
#undef STAGE_PH2
#undef STAGE_PH3
#undef STAGE_PH4
#undef VMW
}

// ================= GEMM 2-phase: BM=128 x BN=256, merged phases, 16 MFMA/phase =================
// For the out-projection. v3@BM=128 ran 8-MFMA phases against constant per-phase barrier+LDS
// latency -> ~18% MfmaUtil, ~73us. Merge: ph1 = Q(0,0)+Q(0,1) (reads A-half0 + ALL B into regs);
// ph2 = Q(1,1)+Q(1,0) (reads A-half1, REUSES b0/b1 regs). 16 MFMA/phase, same 16 ds_reads/K-tile,
// half the barrier pairs. Staging ledger (steady state, queue simulated):
//   issue order/iter: S1@g1a=[buf1.AP64], S5a@g2a=[buf0n.AP0+4B], S1'@g1b=[buf0n.AP64],
//                     S5b@g2b=[buf1n.AP0+4B]
//   vmcnt(5)@g1a forces S5a(i-1)+S1'(i-1) = buf0 complete (5 remain = S5b(i-1));
//   vmcnt(5)@g1b forces S5b(i-1)+S1(i)   = buf1 complete.  Region-free proof: every restage
//   sits >=1 full barrier after its last ds_read's completing lgkmcnt(0).
// Prologue stages tile1 with 5 calls (AP64 deferred to g1a(0)) so iter0 == steady state.
// Peel: no S5/S1' stages; g1b drains vmcnt(0); g1a still issues tile31's AP64.
template<int M, int N, int K, bool BF16_OUT>
__global__ __launch_bounds__(512, 2) void gemm2p(const unsigned short* __restrict__ A,
                                                 const unsigned short* __restrict__ W,
                                                 void* __restrict__ Cout) {
  __shared__ __align__(16) unsigned short Abuf[2][128 * 64];
  __shared__ __align__(16) unsigned short Bbuf[2][256 * 64];
  const int tid = threadIdx.x;
  const int lane = tid & 63;
  const int wv = tid >> 6;
  const int g = lane >> 4;
  const int c = lane & 15;
  const int cs = c & 7;
  const int wm = wv >> 2;
  const int wn = wv & 3;

  constexpr int NT = N / 256;
  constexpr int NWG = (M / 128) * NT;
  constexpr int CHUNK = NWG / 8;
  const int bid = blockIdx.x;
  const int swz = (bid & 7) * CHUNK + (bid >> 3);
  const int m0 = (swz / NT) * 128;
  const int n0 = (swz % NT) * 256;

  const int prl = wv * 8 + (lane >> 3);
  const int scl = lane & 7;
#define STA_P(BUF, P0, KO) { \
    int pr_ = (P0) + prl; \
    int lr_ = ((pr_ >> 5) & 1) * 64 + ((pr_ >> 6) & 1) * 32 + (pr_ & 31); \
    int lc_ = (scl ^ (pr_ & 7)) * 8; \
    gll16(&A[(size_t)(m0 + lr_) * K + (KO) + lc_], &Abuf[BUF][(P0) * 64 + wv * 512]); }
#define STB_P(BUF, P0, KO) { \
    int pr_ = (P0) + prl; \
    int lr_ = ((pr_ >> 5) & 3) * 64 + ((pr_ >> 7) & 1) * 32 + (pr_ & 31); \
    int lc_ = (scl ^ (pr_ & 7)) * 8; \
    gll16(&W[(size_t)(n0 + lr_) * K + (KO) + lc_], &Bbuf[BUF][(P0) * 64 + wv * 512]); }
#define STB4_P(BUF, KO) { STB_P(BUF, 0, KO); STB_P(BUF, 64, KO); STB_P(BUF, 128, KO); STB_P(BUF, 192, KO); }
#define LDA_P(BUF, QM) { \
    _Pragma("unroll") for (int ii = 0; ii < 2; ii++) { \
      _Pragma("unroll") for (int ks = 0; ks < 2; ks++) \
        a[ii][ks] = *(const short8*)&Abuf[BUF][((QM)*64 + wm*32 + ii*16 + c)*64 + (((ks*4+g)^cs)*8)]; } }
#define LDB_P(BUF, QN, BB) { \
    _Pragma("unroll") for (int jj = 0; jj < 2; jj++) { \
      _Pragma("unroll") for (int ks = 0; ks < 2; ks++) \
        BB[jj][ks] = *(const short8*)&Bbuf[BUF][((QN)*128 + wn*32 + jj*16 + c)*64 + (((ks*4+g)^cs)*8)]; } }
#define MM_P(QM, QN, BB) { \
    _Pragma("unroll") for (int ii = 0; ii < 2; ii++) { \
      _Pragma("unroll") for (int jj = 0; jj < 2; jj++) { \
        f32x4 t_ = __builtin_amdgcn_mfma_f32_16x16x32_bf16(a[ii][0], BB[jj][0], acc[(QM)*2+ii][(QN)*2+jj], 0, 0, 0); \
        acc[(QM)*2+ii][(QN)*2+jj] = __builtin_amdgcn_mfma_f32_16x16x32_bf16(a[ii][1], BB[jj][1], t_, 0, 0, 0); } } }
#define VMW5 { asm volatile("s_waitcnt vmcnt(5)" ::: "memory"); SBAR; }

  short8 a[2][2], b0[2][2], b1[2][2];
  f32x4 acc[4][4];
#pragma unroll
  for (int i = 0; i < 4; i++)
#pragma unroll
    for (int j = 0; j < 4; j++) acc[i][j] = (f32x4)0.0f;

  // prologue: tile0 full (6 calls), tile1 partial (5; AP64 deferred to g1a(0))
  STA_P(0, 0, 0); STA_P(0, 64, 0); STB4_P(0, 0);
  STA_P(1, 0, 64); STB4_P(1, 64);
  asm volatile("s_waitcnt vmcnt(5)" ::: "memory");   // tile0 landed (oldest 6 of 11)
  __builtin_amdgcn_s_barrier();

  constexpr int NITER = K / 128;   // 16
  for (int it = 0; it < NITER - 1; ++it) {
    const int kB1 = it * 128 + 64;    // this iter's buf1 tile (2it+1)
    const int kN0 = it * 128 + 128;   // buf0-next (2it+2)
    const int kN1 = it * 128 + 192;   // buf1-next (2it+3)
    // ---- g1a: wait buf0 complete; finish buf1's AP64; read buf0 ----
    VMW5;
    STA_P(1, 64, kB1);
    LDA_P(0, 0); LDB_P(0, 0, b0); LDB_P(0, 1, b1);
    PH_SYNC; MM_P(0, 0, b0); MM_P(0, 1, b1); PH_END;    // ph1: 16 MFMA
    // ---- g2a: stage buf0-next (5); read A-half1 ----
    STA_P(0, 0, kN0); STB4_P(0, kN0);
    LDA_P(0, 1);
    PH_SYNC; MM_P(1, 1, b1); MM_P(1, 0, b0); PH_END;    // ph2: 16 MFMA (B regs reused)
    // ---- g1b: wait buf1 complete; buf0-next AP64; read buf1 ----
    VMW5;
    STA_P(0, 64, kN0);
    LDA_P(1, 0); LDB_P(1, 0, b0); LDB_P(1, 1, b1);
    PH_SYNC; MM_P(0, 0, b0); MM_P(0, 1, b1); PH_END;    // ph3
    // ---- g2b: stage buf1-next (5); read A-half1 ----
    STA_P(1, 0, kN1); STB4_P(1, kN1);
    LDA_P(1, 1);
    PH_SYNC; MM_P(1, 1, b1); MM_P(1, 0, b0); PH_END;    // ph4
  }
  // ---- peel: tiles 30 (buf0), 31 (buf1) ----
  VMW5;
  STA_P(1, 64, (NITER - 1) * 128 + 64);                  // tile31's AP64
  LDA_P(0, 0); LDB_P(0, 0, b0); LDB_P(0, 1, b1);
  PH_SYNC; MM_P(0, 0, b0); MM_P(0, 1, b1); PH_END;
  LDA_P(0, 1);
  PH_SYNC; MM_P(1, 1, b1); MM_P(1, 0, b0); PH_END;
  asm volatile("s_waitcnt vmcnt(0)" ::: "memory"); SBAR; // drain: buf1 fully landed
  LDA_P(1, 0); LDB_P(1, 0, b0); LDB_P(1, 1, b1);
  PH_SYNC; MM_P(0, 0, b0); MM_P(0, 1, b1); PH_END;
  LDA_P(1, 1);
  PH_SYNC; MM_P(1, 1, b1); MM_P(1, 0, b0); PH_END;

  // epilogue: identical mapping to gemm8 BM=128 (verified)
#pragma unroll
  for (int I = 0; I < 4; I++)
#pragma unroll
    for (int J = 0; J < 4; J++)
#pragma unroll
      for (int r = 0; r < 4; r++) {
        int row = m0 + wm * 64 + I * 16 + g * 4 + r;
        int col = n0 + wn * 64 + J * 16 + c;
        if (BF16_OUT)
          ((unsigned short*)Cout)[(size_t)row * N + col] = f2bf(acc[I][J][r]);
        else
          ((float*)Cout)[(size_t)row * N + col] = acc[I][J][r];
      }
#undef STA_P
#undef STB_P
#undef STB4_P
#undef LDA_P
#undef LDB_P
#undef MM_P
#undef VMW5
}

// ---------------- fused RMSNorm+RoPE (blocks 0..4095) and V-transpose (blocks 4096..4607) ----------------
__global__ __launch_bounds__(256) void rope_and_vt(const unsigned short* __restrict__ qkv,
                                                   const float* __restrict__ cosT,
                                                   const float* __restrict__ sinT,
                                                   const float* __restrict__ q_scale,
                                                   const float* __restrict__ k_scale,
                                                   unsigned short* __restrict__ Qb,
                                                   unsigned short* __restrict__ Kb,
                                                   unsigned short* __restrict__ Vt) {
  __shared__ unsigned short lds[128 * 65];
  const int tid = threadIdx.x;
  if (blockIdx.x < 4096) {
    const int lane = tid & 63;
    const int wvq = tid >> 6;
    const int row = blockIdx.x;   // b*T + t
    const int b = row >> 11;
    const int t = row & 2047;
    const int d0 = lane * 2;

    const float2v cs = *(const float2v*)&cosT[t * 128 + d0];
    const float2v sn = *(const float2v*)&sinT[t * 128 + d0];
    const float2v qsc = *(const float2v*)&q_scale[d0];
    const float2v ksc = *(const float2v*)&k_scale[d0];
    const float sgn = (lane < 32) ? -1.0f : 1.0f;
    const unsigned short* base = qkv + (size_t)row * 4096;

#pragma unroll
    for (int s6 = 0; s6 < 6; s6++) {
      const int slot = wvq * 6 + s6;
      const bool isQ = slot < 16;
      const unsigned short* src = base + (isQ ? slot * 128 : 2048 + (slot - 16) * 128);
      ushort2v u = *(const ushort2v*)&src[d0];
      float x0 = bf2f(u.x), x1 = bf2f(u.y);
      float ss = x0 * x0 + x1 * x1;
      ss += __shfl_xor(ss, 1);  ss += __shfl_xor(ss, 2);  ss += __shfl_xor(ss, 4);
      ss += __shfl_xor(ss, 8);  ss += __shfl_xor(ss, 16); ss += __shfl_xor(ss, 32);
      float rinv = rsqrtf(ss * (1.0f / 128.0f) + 1e-6f);
      float2v scv = isQ ? qsc : ksc;
      float xn0 = x0 * rinv * scv.x;
      float xn1 = x1 * rinv * scv.y;
      float o0 = __shfl_xor(xn0, 32);
      float o1 = __shfl_xor(xn1, 32);
      float r0v = xn0 * cs.x + sgn * o0 * sn.x;
      float r1v = xn1 * cs.y + sgn * o1 * sn.y;
      ushort2v out; out.x = f2bf(r0v); out.y = f2bf(r1v);
      unsigned short* dst;
      if (isQ) dst = Qb + ((size_t)(b * HQ_ + slot) * T_ + t) * HD_;
      else     dst = Kb + ((size_t)(b * HKV_ + (slot - 16)) * T_ + t) * HD_;
      *(ushort2v*)&dst[d0] = out;
    }
  } else {
    const int blk = blockIdx.x - 4096;     // 0..511
    const int tblk = blk & 31;
    const int kv = (blk >> 5) & 7;
    const int b = blk >> 8;
    const int t0 = tblk * 64;
    const int r = tid >> 2;
    const int seg = tid & 3;
    const unsigned short* src = qkv + (size_t)(b * T_ + t0 + r) * 4096 + 3072 + kv * 128;
    for (int i = 0; i < 4; i++) {
      int cc = seg * 32 + i * 8;
      ushort8 v = *(const ushort8*)&src[cc];
      for (int q = 0; q < 8; q++) lds[(cc + q) * 65 + r] = v[q];
    }
    __syncthreads();
    const int cI = tid >> 1;
    const int rs = (tid & 1) * 32;
    unsigned short* dst = Vt + ((size_t)(b * HKV_ + kv) * HD_ + cI) * T_ + t0 + rs;
    const unsigned short* srow = &lds[cI * 65 + rs];
    for (int j = 0; j < 32; j += 4) {
      ushort4v v; v.x = srow[j]; v.y = srow[j + 1]; v.z = srow[j + 2]; v.w = srow[j + 3];
      *(ushort4v*)&dst[j] = v;
    }
  }
}

// ---------------- Flash attention v5: double-buffered K/V, uniform work (verified) ----------------
__global__ __launch_bounds__(256) void attn(const unsigned short* __restrict__ Qb,
                                            const unsigned short* __restrict__ Kb,
                                            const unsigned short* __restrict__ Vt,
                                            unsigned short* __restrict__ ctxb) {
  __shared__ __align__(16) unsigned short Ks[2][64 * 128];  // [key][hd], chunk-swizzled
  __shared__ __align__(16) unsigned short Vs[2][128 * 64];  // [hd][key], chunk-swizzled
  __shared__ __align__(16) unsigned short Ps[4][16 * 72];   // per-wave P, stride 72 (pad)
  const int tid = threadIdx.x;
  const int lane = tid & 63;
  const int wv = tid >> 6;
  const int g = lane >> 4;
  const int c = lane & 15;

  const int blk = blockIdx.x;            // 0..511
  const int kv = blk & 7;
  const int idx = blk >> 3;              // 0..63
  const int p = idx >> 2;                // 0..15 pair index
  const int b = (idx >> 1) & 1;
  const int h = kv * 2 + (idx & 1);

  const unsigned short* Kh = Kb + (size_t)(b * HKV_ + kv) * T_ * HD_;
  const unsigned short* Vh = Vt + (size_t)(b * HKV_ + kv) * HD_ * T_;
  const float scale = 0.08838834764831845f;  // 1/sqrt(128)

#define STAGE_KV(BF, KT) { \
  _Pragma("unroll") for (int i_ = 0; i_ < 4; i_++) { \
    const int ch_ = wv * 256 + i_ * 64 + lane; \
    const int rK_ = ch_ >> 4, cK_ = ch_ & 15; \
    gll16(Kh + (size_t)((KT) * 64 + rK_) * HD_ + (cK_ ^ (rK_ & 7)) * 8, \
          Ks[BF] + (size_t)(wv * 256 + i_ * 64) * 8); \
    const int rV_ = ch_ >> 3, cV_ = ch_ & 7; \
    gll16(Vh + (size_t)rV_ * T_ + (KT) * 64 + (cV_ ^ (rV_ & 7)) * 8, \
          Vs[BF] + (size_t)(wv * 256 + i_ * 64) * 8); } }

  for (int ph = 0; ph < 2; ph++) {
    const int qb = ph ? (31 - p) : p;    // 64-row q-block index
    const int nkt = qb + 1;
    const unsigned short* Qh = Qb + ((size_t)(b * HQ_ + h) * T_ + qb * 64 + wv * 16) * HD_;

    short8 aq[4];
#pragma unroll
    for (int dk = 0; dk < 4; dk++) aq[dk] = *(const short8*)&Qh[c * HD_ + dk * 32 + g * 8];

    f32x4 acc[8];
#pragma unroll
    for (int dc = 0; dc < 8; dc++) acc[dc] = (f32x4)0.0f;
    float lp[4] = {0.0f, 0.0f, 0.0f, 0.0f};

    STAGE_KV(0, 0);
    __syncthreads();

    for (int kt = 0; kt < nkt; kt++) {
      const int cur = kt & 1;
      if (kt + 1 < nkt) { STAGE_KV(cur ^ 1, kt + 1); }   // block-uniform condition
      __builtin_amdgcn_sched_barrier(0);                 // pin stage-issue before compute

      f32x4 s[4];
#pragma unroll
      for (int kf = 0; kf < 4; kf++) s[kf] = (f32x4)0.0f;
      __builtin_amdgcn_s_setprio(1);
#pragma unroll
      for (int dk = 0; dk < 4; dk++) {
#pragma unroll
        for (int kf = 0; kf < 4; kf++) {
          short8 bk = *(const short8*)&Ks[cur][(kf * 16 + c) * 128 + ((dk * 4 + g) ^ (c & 7)) * 8];
          s[kf] = __builtin_amdgcn_mfma_f32_16x16x32_bf16(aq[dk], bk, s[kf], 0, 0, 0);
        }
      }
      __builtin_amdgcn_s_setprio(0);

      const bool diag = (kt == nkt - 1);
#pragma unroll
      for (int kf = 0; kf < 4; kf++) {
#pragma unroll
        for (int r = 0; r < 4; r++) {
          float pv = __expf(s[kf][r] * scale);
          if (diag) {
            int key = kt * 64 + kf * 16 + c;
            int rowq = qb * 64 + wv * 16 + g * 4 + r;
            if (key > rowq) pv = 0.0f;
          }
          lp[r] += pv;
          Ps[wv][(g * 4 + r) * 72 + kf * 16 + c] = f2bf(pv);
        }
      }

      short8 ap[2];
      ap[0] = *(const short8*)&Ps[wv][c * 72 + g * 8];
      ap[1] = *(const short8*)&Ps[wv][c * 72 + 32 + g * 8];
      __builtin_amdgcn_s_setprio(1);
#pragma unroll
      for (int dc = 0; dc < 8; dc++) {
#pragma unroll
        for (int kf2 = 0; kf2 < 2; kf2++) {
          short8 bv = *(const short8*)&Vs[cur][(dc * 16 + c) * 64 + ((kf2 * 4 + g) ^ (c & 7)) * 8];
          acc[dc] = __builtin_amdgcn_mfma_f32_16x16x32_bf16(ap[kf2], bv, acc[dc], 0, 0, 0);
        }
      }
      __builtin_amdgcn_s_setprio(0);

      __syncthreads();   // drains vmcnt(0): kt+1's tile landed; buf cur free for kt+2
    }

#pragma unroll
    for (int r = 0; r < 4; r++) {
      float l = lp[r];
      l += __shfl_xor(l, 1); l += __shfl_xor(l, 2);
      l += __shfl_xor(l, 4); l += __shfl_xor(l, 8);
      float inv = 1.0f / l;
      int row = b * T_ + qb * 64 + wv * 16 + g * 4 + r;
#pragma unroll
      for (int dc = 0; dc < 8; dc++)
        ctxb[(size_t)row * (HQ_ * HD_) + h * HD_ + dc * 16 + c] = f2bf(acc[dc][r] * inv);
    }
  }
#undef STAGE_KV
}

extern "C" void kernel_launch(void* const* d_in, const int* in_sizes, int n_in,
                              void* d_out, int out_size, void* d_ws, size_t ws_size,
                              hipStream_t stream) {
  const float* x = (const float*)d_in[0];
  const float* cosT = (const float*)d_in[2];
  const float* sinT = (const float*)d_in[3];
  const float* Wq = (const float*)d_in[4];
  const float* Wk = (const float*)d_in[5];
  const float* Wv = (const float*)d_in[6];
  const float* Wo = (const float*)d_in[7];
  const float* q_scale = (const float*)d_in[8];
  const float* k_scale = (const float*)d_in[9];

  char* ws = (char*)d_ws;
  unsigned short* qkv  = (unsigned short*)(ws + 0);
  unsigned short* ctxb = qkv;                                  // alias: qkv dead before attn
  unsigned short* xb   = (unsigned short*)(ws + 33554432);
  unsigned short* wqkv = (unsigned short*)(ws + 50331648);
  unsigned short* wob  = (unsigned short*)(ws + 67108864);
  unsigned short* Qb   = (unsigned short*)(ws + 75497472);
  unsigned short* Kb   = (unsigned short*)(ws + 92274688);
  unsigned short* Vt   = (unsigned short*)(ws + 100663296);

  cast_all<<<5120, 256, 0, stream>>>(x, Wq, Wk, Wv, Wo, xb, wqkv, wob);
  gemm8<256, 4096, 4096, 2048, true><<<256, 512, 0, stream>>>(xb, wqkv, qkv);
  rope_and_vt<<<4608, 256, 0, stream>>>(qkv, cosT, sinT, q_scale, k_scale, Qb, Kb, Vt);
  attn<<<512, 256, 0, stream>>>(Qb, Kb, Vt, ctxb);
  gemm2p<4096, 2048, 2048, false><<<256, 512, 0, stream>>>(ctxb, wob, d_out);
}